// Round 1
// baseline (193.285 us; speedup 1.0000x reference)
//
#include <hip/hip_runtime.h>

typedef __bf16 bf16x8 __attribute__((ext_vector_type(8)));
typedef float floatx4 __attribute__((ext_vector_type(4)));

// split fp32 -> bf16 hi + bf16 lo (x ~= hi + lo, residual ~2^-17)
__device__ inline void cvt8v(float4 v0, float4 v1, bf16x8& h, bf16x8& l){
  float v[8] = {v0.x, v0.y, v0.z, v0.w, v1.x, v1.y, v1.z, v1.w};
  #pragma unroll
  for (int i = 0; i < 8; ++i) {
    __bf16 hi = (__bf16)v[i];
    h[i] = hi;
    l[i] = (__bf16)(v[i] - (float)hi);
  }
}

// async global->LDS, 16B per lane. LDS dest must be wave-uniform base; HW
// writes base + lane*16. Global src is per-lane.
__device__ inline void gload_lds16(const float* g, float* l){
  __builtin_amdgcn_global_load_lds(
      (const __attribute__((address_space(1))) unsigned int*)g,
      (__attribute__((address_space(3))) unsigned int*)l, 16, 0, 0);
}

// ---------------------------------------------------------------------------
// K1 v7: mod[b,ff] = xt * silu(xg). M=64, N=8192, K=1024.
// 512 blocks x 512 threads (8 waves). wave = (khalf<<2)|wtile:
//   wtile in [0,4): b-rows 16*wtile..+16 ; khalf in [0,2): K-half 512.
// W streams via global_load_lds (width 16) into double-buffered LDS tiles
// [16 ff][128 k] fp32, XOR-swizzled (byte ^= (row&7)<<4) via pre-swizzled
// GLOBAL source + swizzled ds_read (linear LDS dest, rule 21).
// One __syncthreads per 128-K chunk (m97 structure). K-half combine via 8KB
// LDS. K1b folded in: per-quad shfl reduction of |mod| + atomicAdd to sums.
// ---------------------------------------------------------------------------
__global__ __launch_bounds__(512, 4) void k1_gemm(
    const float* __restrict__ x,
    const float* __restrict__ Wt,
    const float* __restrict__ Wg,
    float* __restrict__ mod,
    float* __restrict__ sums)
{
  __shared__ __align__(16) float wlds[2][2][2][16 * 128];  // [buf][half][mat] 64 KB
  __shared__ __align__(16) float red[4][64][8];            // 8 KB

  const int tid   = threadIdx.x;
  const int wave  = tid >> 6, lane = tid & 63;
  const int wtile = wave & 3;
  const int khalf = wave >> 2;
  const int quad  = lane >> 4, r16 = lane & 15;
  const int ffbase = blockIdx.x * 16;
  const int kbase  = khalf * 512;

  // staging: wave issues 4 gload_lds per chunk (2 per matrix).
  // instr j covers tile rows {2j, 2j+1}; this wave owns j0=2*wtile, j1=j0+1.
  const int j0 = 2 * wtile, j1 = j0 + 1;
  const int row0 = 2 * j0 + (lane >> 5);
  const int row1 = 2 * j1 + (lane >> 5);
  const int cbyte = (lane & 31) * 16;
  // pre-swizzled global source column (bytes): cb ^ ((row&7)<<4)
  const int src_f0 = (ffbase + row0) * 1024 + kbase + ((cbyte ^ ((row0 & 7) << 4)) >> 2);
  const int src_f1 = (ffbase + row1) * 1024 + kbase + ((cbyte ^ ((row1 & 7) << 4)) >> 2);

  // x (A-operand) per-lane source: row = wtile*16 + r16, k-base = quad*8
  const float* xsrc = x + (wtile * 16 + r16) * 1024 + kbase + quad * 8;

  // B-operand read swizzle: row byte + (colbyte ^ xr)
  const int rowb = r16 * 512;
  const int xr   = (r16 & 7) << 4;

  floatx4 accT = (floatx4)0.0f, accG = (floatx4)0.0f;

  auto STAGE = [&](int buf, int kc) {
    gload_lds16(Wt + src_f0 + kc, &wlds[buf][khalf][0][0] + j0 * 256);
    gload_lds16(Wt + src_f1 + kc, &wlds[buf][khalf][0][0] + j1 * 256);
    gload_lds16(Wg + src_f0 + kc, &wlds[buf][khalf][1][0] + j0 * 256);
    gload_lds16(Wg + src_f1 + kc, &wlds[buf][khalf][1][0] + j1 * 256);
  };

  STAGE(0, 0);
  __syncthreads();

  #pragma unroll
  for (int it = 0; it < 4; ++it) {
    const int kc = it * 128;
    // issue x fragment loads for this chunk first (L2-resident, 8x16B)
    float4 xv[4][2];
    #pragma unroll
    for (int ks = 0; ks < 4; ++ks) {
      xv[ks][0] = *reinterpret_cast<const float4*>(xsrc + kc + ks * 32);
      xv[ks][1] = *reinterpret_cast<const float4*>(xsrc + kc + ks * 32 + 4);
    }
    // then issue next chunk's async staging (stays in flight under compute)
    if (it < 3) STAGE((it + 1) & 1, kc + 128);

    const char* tT = (const char*)&wlds[it & 1][khalf][0][0];
    const char* tG = (const char*)&wlds[it & 1][khalf][1][0];
    #pragma unroll
    for (int ks = 0; ks < 4; ++ks) {
      const int c0  = ks * 128 + quad * 32;
      const int aLo = rowb + (c0 ^ xr);
      const int aHi = rowb + ((c0 + 16) ^ xr);
      bf16x8 ah, al, bth, btl, bgh, bgl;
      cvt8v(xv[ks][0], xv[ks][1], ah, al);
      cvt8v(*reinterpret_cast<const float4*>(tT + aLo),
            *reinterpret_cast<const float4*>(tT + aHi), bth, btl);
      cvt8v(*reinterpret_cast<const float4*>(tG + aLo),
            *reinterpret_cast<const float4*>(tG + aHi), bgh, bgl);
      accT = __builtin_amdgcn_mfma_f32_16x16x32_bf16(ah, bth, accT, 0, 0, 0);
      accT = __builtin_amdgcn_mfma_f32_16x16x32_bf16(ah, btl, accT, 0, 0, 0);
      accT = __builtin_amdgcn_mfma_f32_16x16x32_bf16(al, bth, accT, 0, 0, 0);
      accG = __builtin_amdgcn_mfma_f32_16x16x32_bf16(ah, bgh, accG, 0, 0, 0);
      accG = __builtin_amdgcn_mfma_f32_16x16x32_bf16(ah, bgl, accG, 0, 0, 0);
      accG = __builtin_amdgcn_mfma_f32_16x16x32_bf16(al, bgh, accG, 0, 0, 0);
    }
    __syncthreads();
  }

  // ---- combine K-halves, apply silu, write mod, accumulate |mod| sums ----
  if (khalf == 1) {
    #pragma unroll
    for (int r = 0; r < 4; ++r) {
      red[wtile][lane][r]     = accT[r];
      red[wtile][lane][4 + r] = accG[r];
    }
  }
  __syncthreads();
  if (khalf == 0) {
    const int kg = ffbase >> 11;
    #pragma unroll
    for (int r = 0; r < 4; ++r) {
      float t = accT[r] + red[wtile][lane][r];
      float g = accG[r] + red[wtile][lane][4 + r];
      float sig = 1.0f / (1.0f + __expf(-g));
      float m = t * g * sig;
      const int b = wtile * 16 + quad * 4 + r;   // C/D: row = quad*4 + reg
      mod[b * 8192 + ffbase + r16] = m;
      float a = fabsf(m);
      a += __shfl_xor(a, 1, 64);
      a += __shfl_xor(a, 2, 64);
      a += __shfl_xor(a, 4, 64);
      a += __shfl_xor(a, 8, 64);
      if (r16 == 0) atomicAdd(&sums[b * 4 + kg], a);
    }
  }
}

// ---------------------------------------------------------------------------
// K2: partial[b*8+jc] = block sum of sqrt(re^2+im^2+eps). No atomics.
// s computed inline from raw |mod| sums.
// ---------------------------------------------------------------------------
__global__ __launch_bounds__(256) void k2_mag(
    const float* __restrict__ mod, const float* __restrict__ sums,
    const float* __restrict__ wstat,
    const float* __restrict__ wmod,
    const float* __restrict__ cw,
    const float* __restrict__ cb,
    float* __restrict__ partial)
{
  const int b = blockIdx.x, jc = blockIdx.y;
  const int tid = threadIdx.x;
  __shared__ __align__(16) float a_l[256 * 8];

  float weff[4]; float beff = 0.0f;
  #pragma unroll
  for (int r = 0; r < 4; ++r) {
    weff[r] = cw[r] + cw[4 + r] + cw[8 + r] + cw[12 + r];
    beff += cb[r];
  }
  const float s0 = rsqrtf(sums[b * 4 + 0] * (1.0f / 2048.0f) + 1e-4f);
  const float s1 = rsqrtf(sums[b * 4 + 1] * (1.0f / 2048.0f) + 1e-4f);
  const float* mb = mod + b * 8192;

  #pragma unroll
  for (int p = 0; p < 8; ++p) {              // p = (k,r); tid = i  (coalesced)
    int k = p >> 2, r = p & 3;
    float sc = (k ? s1 : s0) * weff[r];
    a_l[tid * 8 + p] = mb[k * 2048 + r * 512 + tid] * sc;
  }
  const int j = jc * 32 + (tid & 31);
  float bp[8];
  #pragma unroll
  for (int p = 0; p < 8; ++p) {
    int k = p >> 2, r = p & 3;
    bp[p] = mb[k * 2048 + r * 512 + 256 + j] * (k ? s1 : s0);
  }
  __syncthreads();

  const int ioff = tid >> 5;
  float acc = 0.0f;
  for (int it = 0; it < 32; ++it) {
    const int i = it * 8 + ioff;
    const float4 av0 = *reinterpret_cast<const float4*>(&a_l[i * 8]);
    const float4 av1 = *reinterpret_cast<const float4*>(&a_l[i * 8 + 4]);
    float d0 = av0.x * bp[0] + av0.y * bp[1] + av0.z * bp[2] + av0.w * bp[3];
    float d1 = av1.x * bp[4] + av1.y * bp[5] + av1.z * bp[6] + av1.w * bp[7];
    const int ij = i * 256 + j;
    float m0 = wmod[ij] * (d0 + beff);
    float m1 = wmod[65536 + ij] * (d1 + beff);
    float2 a1 = *reinterpret_cast<const float2*>(wstat + 131072 + ij * 2);
    float re = a1.x * m0 - a1.y * m1;
    float im = a1.x * m1 - a1.y * m0;
    acc += sqrtf(re * re + im * im + 1e-4f);
  }
  #pragma unroll
  for (int o = 1; o < 64; o <<= 1) acc += __shfl_xor(acc, o, 64);
  __shared__ float wsum[4];
  if ((tid & 63) == 0) wsum[tid >> 6] = acc;
  __syncthreads();
  if (tid == 0) partial[b * 8 + jc] = wsum[0] + wsum[1] + wsum[2] + wsum[3];
}

// ---------------------------------------------------------------------------
// K4: final output (fp32). grid (64 b, 8 i-chunks of 32). 2 j's per thread,
// float2 stores. magsum = sum of 8 partials in preamble.
// ---------------------------------------------------------------------------
__global__ __launch_bounds__(256) void k4_out(
    const float* __restrict__ mod, const float* __restrict__ sums,
    const float* __restrict__ wstat,
    const float* __restrict__ wmod,
    const float* __restrict__ cw,
    const float* __restrict__ cb,
    const float* __restrict__ partial,
    float* __restrict__ out)
{
  const int b = blockIdx.x, ibase = blockIdx.y * 32;
  const int tid = threadIdx.x;
  __shared__ __align__(16) float a_l[32 * 16];

  float weff[4]; float beff = 0.0f;
  #pragma unroll
  for (int r = 0; r < 4; ++r) {
    weff[r] = cw[r] + cw[4 + r] + cw[8 + r] + cw[12 + r];
    beff += cb[r];
  }
  float sk[4];
  #pragma unroll
  for (int k = 0; k < 4; ++k)
    sk[k] = rsqrtf(sums[b * 4 + k] * (1.0f / 2048.0f) + 1e-4f);
  const float* mb = mod + b * 8192;

  float tot = 0.0f;
  #pragma unroll
  for (int t = 0; t < 8; ++t) tot += partial[b * 8 + t];
  const float inv = rsqrtf(tot * (1.0f / 65536.0f) + 1e-4f);

  #pragma unroll
  for (int p = 0; p < 2; ++p) {
    int idx = p * 256 + tid;
    int il = idx & 31, kr = idx >> 5;
    int k = kr >> 2, r = kr & 3;
    a_l[il * 16 + kr] = mb[k * 2048 + r * 512 + ibase + il] * (sk[k] * weff[r]);
  }
  const int j = (tid & 127) * 2;
  const int ioff = tid >> 7;
  float bp0[16], bp1[16];
  #pragma unroll
  for (int kr = 0; kr < 16; ++kr) {
    int k = kr >> 2, r = kr & 3;
    float2 v = *reinterpret_cast<const float2*>(mb + k * 2048 + r * 512 + 256 + j);
    bp0[kr] = v.x * sk[k]; bp1[kr] = v.y * sk[k];
  }
  __syncthreads();

  #pragma unroll 2
  for (int it = 0; it < 16; ++it) {
    const int il = it * 2 + ioff;
    const int i = ibase + il;
    const float4 a0 = *reinterpret_cast<const float4*>(&a_l[il * 16]);
    const float4 a1 = *reinterpret_cast<const float4*>(&a_l[il * 16 + 4]);
    const float4 a2 = *reinterpret_cast<const float4*>(&a_l[il * 16 + 8]);
    const float4 a3 = *reinterpret_cast<const float4*>(&a_l[il * 16 + 12]);
    const int ij = i * 256 + j;
    const float2 wm0 = *reinterpret_cast<const float2*>(wmod + ij);
    const float2 wm1 = *reinterpret_cast<const float2*>(wmod + 65536 + ij);
    const float2 wm2 = *reinterpret_cast<const float2*>(wmod + 131072 + ij);
    const float2 wm3 = *reinterpret_cast<const float2*>(wmod + 196608 + ij);
    const float4 A0v = *reinterpret_cast<const float4*>(wstat + ij * 2);
    const float4 A1v = *reinterpret_cast<const float4*>(wstat + 131072 + ij * 2);
    float outv[2];
    #pragma unroll
    for (int e = 0; e < 2; ++e) {
      const float* bp = e ? bp1 : bp0;
      float d0 = a0.x * bp[0] + a0.y * bp[1] + a0.z * bp[2] + a0.w * bp[3];
      float d1 = a1.x * bp[4] + a1.y * bp[5] + a1.z * bp[6] + a1.w * bp[7];
      float d2 = a2.x * bp[8] + a2.y * bp[9] + a2.z * bp[10] + a2.w * bp[11];
      float d3 = a3.x * bp[12] + a3.y * bp[13] + a3.z * bp[14] + a3.w * bp[15];
      float m0 = (e ? wm0.y : wm0.x) * (d0 + beff);
      float m1 = (e ? wm1.y : wm1.x) * (d1 + beff);
      float m2 = (e ? wm2.y : wm2.x) * (d2 + beff);
      float m3 = (e ? wm3.y : wm3.x) * (d3 + beff);
      float A0r = e ? A0v.z : A0v.x;
      float A0i = e ? A0v.w : A0v.y;
      float A1r = e ? A1v.z : A1v.x;
      float A1i = e ? A1v.w : A1v.y;
      float re = A1r * m0 - A1i * m1;
      float im = A1r * m1 - A1i * m0;
      float mwre = A0r + re * inv;
      float mwim = A0i + im * inv;
      float rd = rsqrtf(m2 * m2 + m3 * m3 + 1e-4f);
      outv[e] = (mwre * m2 + mwim * m3) * rd;
    }
    *reinterpret_cast<float2*>(out + b * 65536 + ij) = make_float2(outv[0], outv[1]);
  }
}

extern "C" void kernel_launch(void* const* d_in, const int* in_sizes, int n_in,
                              void* d_out, int out_size, void* d_ws, size_t ws_size,
                              hipStream_t stream) {
  const float* x     = (const float*)d_in[0];
  const float* Wt    = (const float*)d_in[1];
  const float* Wg    = (const float*)d_in[2];
  const float* wstat = (const float*)d_in[3];
  const float* wmod  = (const float*)d_in[4];
  const float* cw    = (const float*)d_in[5];
  const float* cb    = (const float*)d_in[6];

  float* mod     = (float*)d_ws;           // 524288 floats
  float* sums    = mod + 524288;           // 256 floats (raw |mod| sums)
  float* partial = sums + 256;             // 512 floats

  hipMemsetAsync(sums, 0, 256 * sizeof(float), stream);
  k1_gemm<<<512, 512, 0, stream>>>(x, Wt, Wg, mod, sums);
  k2_mag <<<dim3(64, 8), 256, 0, stream>>>(mod, sums, wstat, wmod, cw, cb, partial);
  k4_out <<<dim3(64, 8), 256, 0, stream>>>(mod, sums, wstat, wmod, cw, cb, partial,
                                           (float*)d_out);
}